// Round 4
// baseline (112.767 us; speedup 1.0000x reference)
//
#include <hip/hip_runtime.h>
#include <math.h>

#define D_ 128
#define NTOK 8192
#define CHUNK 64
#define NCB 64        // chunks per batch
#define NCH 128       // total chunks
#define LN_EPS 1e-5f
#define EPS_ATTN 1e-6f

typedef __attribute__((ext_vector_type(8))) short bf16x8;
typedef __attribute__((ext_vector_type(4))) short bf16x4;
typedef __attribute__((ext_vector_type(2))) short bf16x2;
typedef __attribute__((ext_vector_type(4))) float f32x4;

__device__ inline short f2bf(float f) {
  unsigned u = __builtin_bit_cast(unsigned, f);
  u += 0x7fffu + ((u >> 16) & 1u);
  return (short)(u >> 16);
}
__device__ inline float bf2f(short s) {
  unsigned u = ((unsigned)(unsigned short)s) << 16;
  return __builtin_bit_cast(float, u);
}
__device__ inline float phi_(float x) { return x > 0.f ? x + 1.f : __expf(x); }

// ============ K1: LN1 inline + W-transpose inline + QKVG GEMMs (512 blocks) ============
// bid<256: V+G (1 tile, 2 GEMMs); [256,384): Q x2 tiles; [384,512): K x2 tiles
__global__ __launch_bounds__(256) void k_qkvg(const float* __restrict__ tokens,
    const float* __restrict__ Wq, const float* __restrict__ Wk,
    const float* __restrict__ Wv, const float* __restrict__ Wg,
    const float* __restrict__ bgp,
    const float* __restrict__ g1, const float* __restrict__ b1,
    short* __restrict__ Qp, short* __restrict__ Kp, short* __restrict__ KpT,
    short* __restrict__ VgT) {
  const int tid = threadIdx.x, bid = blockIdx.x;
  const int w = tid >> 6, l = tid & 63;
  const int i = l & 15, q = l >> 4;
  __shared__ short xs[32][136];
  __shared__ short wsd[128][136];

  // fp32 [k][n] -> bf16 LDS [n][k].  FULL matrix = 4096 float4 loads
  // = 16 iterations x 256 threads.  (R3 bug: 8 iters filled only n<64.)
  auto stageWT = [&](const float* __restrict__ Wf) {
    #pragma unroll
    for (int it = 0; it < 16; ++it) {
      const int v = it*256 + tid;
      const int k = v & 127, n4 = v >> 7;   // n4 in [0,32)
      const float4 x4 = *(const float4*)&Wf[k*D_ + n4*4];
      wsd[n4*4+0][k] = f2bf(x4.x);
      wsd[n4*4+1][k] = f2bf(x4.y);
      wsd[n4*4+2][k] = f2bf(x4.z);
      wsd[n4*4+3][k] = f2bf(x4.w);
    }
  };
  auto doLN = [&](int m0) {
    const float2 gg = *(const float2*)&g1[l*2];
    const float2 bb = *(const float2*)&b1[l*2];
    float2 tv[8];
    #pragma unroll
    for (int it = 0; it < 8; ++it)
      tv[it] = *(const float2*)&tokens[(m0 + w*8 + it)*D_ + l*2];
    #pragma unroll
    for (int it = 0; it < 8; ++it) {
      const float2 v = tv[it];
      float s = v.x + v.y, qq = v.x*v.x + v.y*v.y;
      #pragma unroll
      for (int off = 1; off < 64; off <<= 1) {
        s += __shfl_xor(s, off); qq += __shfl_xor(qq, off);
      }
      const float mean = s*(1.f/D_);
      const float r2 = rsqrtf(qq*(1.f/D_) - mean*mean + LN_EPS);
      bf16x2 o;
      o.x = f2bf((v.x-mean)*r2*gg.x + bb.x);
      o.y = f2bf((v.y-mean)*r2*gg.y + bb.y);
      *(bf16x2*)&xs[w*8 + it][l*2] = o;
    }
  };
  auto gemm = [&](f32x4 (*acc)[2]) {
    #pragma unroll
    for (int kk = 0; kk < 4; ++kk) {
      bf16x8 a[2], bfr[2];
      #pragma unroll
      for (int mt = 0; mt < 2; ++mt) a[mt] = *(const bf16x8*)&xs[mt*16+i][kk*32+q*8];
      #pragma unroll
      for (int nt = 0; nt < 2; ++nt) bfr[nt] = *(const bf16x8*)&wsd[w*32+nt*16+i][kk*32+q*8];
      #pragma unroll
      for (int mt = 0; mt < 2; ++mt)
        #pragma unroll
        for (int nt = 0; nt < 2; ++nt)
          acc[mt][nt] = __builtin_amdgcn_mfma_f32_16x16x32_bf16(a[mt], bfr[nt], acc[mt][nt], 0, 0, 0);
    }
  };

  if (bid < 256) {
    const int m0 = bid * 32;
    doLN(m0);
    stageWT(Wv);
    __syncthreads();
    f32x4 acc[2][2], accg[2][2];
    #pragma unroll
    for (int mt = 0; mt < 2; ++mt)
      #pragma unroll
      for (int nt = 0; nt < 2; ++nt) acc[mt][nt] = (f32x4){0.f,0.f,0.f,0.f};
    gemm(acc);
    __syncthreads();
    stageWT(Wg);
    __syncthreads();
    #pragma unroll
    for (int mt = 0; mt < 2; ++mt)
      #pragma unroll
      for (int nt = 0; nt < 2; ++nt) accg[mt][nt] = (f32x4){0.f,0.f,0.f,0.f};
    gemm(accg);
    #pragma unroll
    for (int mt = 0; mt < 2; ++mt)
      #pragma unroll
      for (int nt = 0; nt < 2; ++nt) {
        const int h = w*32 + nt*16 + i;
        const int t0 = m0 + mt*16 + 4*q;
        const float bgd = bgp[h];
        bf16x4 o;
        #pragma unroll
        for (int r = 0; r < 4; ++r) {
          const float gv = 1.f/(1.f + __expf(-(accg[mt][nt][r] + bgd)));
          o[r] = f2bf(acc[mt][nt][r] * gv);
        }
        *(bf16x4*)&VgT[h*NTOK + t0] = o;
      }
  } else if (bid < 384) {
    stageWT(Wq);
    for (int uu = 0; uu < 2; ++uu) {
      const int m0 = ((bid - 256)*2 + uu) * 32;
      __syncthreads();
      doLN(m0);
      __syncthreads();
      f32x4 acc[2][2];
      #pragma unroll
      for (int mt = 0; mt < 2; ++mt)
        #pragma unroll
        for (int nt = 0; nt < 2; ++nt) acc[mt][nt] = (f32x4){0.f,0.f,0.f,0.f};
      gemm(acc);
      #pragma unroll
      for (int mt = 0; mt < 2; ++mt)
        #pragma unroll
        for (int nt = 0; nt < 2; ++nt) {
          const int h = w*32 + nt*16 + i;
          #pragma unroll
          for (int r = 0; r < 4; ++r)
            Qp[(m0 + mt*16 + 4*q + r)*D_ + h] = f2bf(phi_(acc[mt][nt][r]));
        }
    }
  } else {
    stageWT(Wk);
    for (int uu = 0; uu < 2; ++uu) {
      const int m0 = ((bid - 384)*2 + uu) * 32;
      __syncthreads();
      doLN(m0);
      __syncthreads();
      f32x4 acc[2][2];
      #pragma unroll
      for (int mt = 0; mt < 2; ++mt)
        #pragma unroll
        for (int nt = 0; nt < 2; ++nt) acc[mt][nt] = (f32x4){0.f,0.f,0.f,0.f};
      gemm(acc);
      #pragma unroll
      for (int mt = 0; mt < 2; ++mt)
        #pragma unroll
        for (int nt = 0; nt < 2; ++nt) {
          const int h = w*32 + nt*16 + i;
          const int t0 = m0 + mt*16 + 4*q;
          bf16x4 o;
          #pragma unroll
          for (int r = 0; r < 4; ++r) {
            const short bv = f2bf(phi_(acc[mt][nt][r]));
            Kp[(t0+r)*D_ + h] = bv;
            o[r] = bv;
          }
          *(bf16x4*)&KpT[h*NTOK + t0] = o;
        }
    }
  }
}

// ============ K2: intra-chunk scores (128 units) + chunk KV^T quarters (512 units) in 512 blocks ============
__global__ __launch_bounds__(256) void k_cs(const short* __restrict__ KpT,
    const short* __restrict__ VgT, const short* __restrict__ Qp,
    const short* __restrict__ Kp,
    float* __restrict__ KVT, float* __restrict__ Ksum,
    short* __restrict__ A, float* __restrict__ rowsum) {
  const int tid = threadIdx.x, bid = blockIdx.x;
  const int w = tid >> 6, l = tid & 63;
  const int i = l & 15, q = l >> 4;
  __shared__ __align__(16) char smem[34816];

  auto chunkkv = [&](int v) {
    const int c = v & 127, hh = (v >> 7) & 1, dh = v >> 8;
    const int tb = c*CHUNK;
    short (*vgl)[72] = (short(*)[72])smem;             // 64 x 72
    short (*kpl)[72] = (short(*)[72])(smem + 9216);    // 64 x 72
    float (*ksp)[5]  = (float(*)[5])(smem + 18432);    // 64 x 5
    for (int u = tid; u < 512; u += 256) {
      const int dd = u >> 3, c8 = (u & 7)*8;
      *(bf16x8*)&vgl[dd][c8] = *(const bf16x8*)&VgT[(dh*64+dd)*NTOK + tb + c8];
      *(bf16x8*)&kpl[dd][c8] = *(const bf16x8*)&KpT[(hh*64+dd)*NTOK + tb + c8];
    }
    __syncthreads();
    f32x4 acc[4];
    #pragma unroll
    for (int nt = 0; nt < 4; ++nt) acc[nt] = (f32x4){0.f,0.f,0.f,0.f};
    #pragma unroll
    for (int kk = 0; kk < 2; ++kk) {
      bf16x8 a = *(const bf16x8*)&vgl[w*16+i][kk*32+q*8];
      #pragma unroll
      for (int nt = 0; nt < 4; ++nt) {
        bf16x8 bb = *(const bf16x8*)&kpl[nt*16+i][kk*32+q*8];
        acc[nt] = __builtin_amdgcn_mfma_f32_16x16x32_bf16(a, bb, acc[nt], 0, 0, 0);
      }
    }
    float* KVc = KVT + (size_t)c*16384;
    #pragma unroll
    for (int nt = 0; nt < 4; ++nt)
      #pragma unroll
      for (int r = 0; r < 4; ++r) {
        const int d = dh*64 + w*16 + 4*q + r;
        const int h = hh*64 + nt*16 + i;
        KVc[d*D_ + h] = acc[nt][r];
      }
    if (dh == 0) {
      const int hq = tid >> 2, part = tid & 3;
      float s = 0.f;
      #pragma unroll
      for (int t = 0; t < 16; ++t) s += bf2f(kpl[hq][part*16 + t]);
      ksp[hq][part] = s;
      __syncthreads();
      if (tid < 64)
        Ksum[c*D_ + hh*64 + tid] = ksp[tid][0]+ksp[tid][1]+ksp[tid][2]+ksp[tid][3];
    }
  };

  auto scores = [&](int c) {
    const int tb = c*CHUNK;
    short (*qpl)[136] = (short(*)[136])smem;            // 64 x 136
    short (*kpl)[136] = (short(*)[136])(smem + 17408);  // 64 x 136
    for (int u = tid; u < 1024; u += 256) {
      const int t = u >> 4, c8 = (u & 15)*8;
      *(bf16x8*)&qpl[t][c8] = *(const bf16x8*)&Qp[(tb+t)*D_ + c8];
      *(bf16x8*)&kpl[t][c8] = *(const bf16x8*)&Kp[(tb+t)*D_ + c8];
    }
    __syncthreads();
    f32x4 acc[4];
    #pragma unroll
    for (int nt = 0; nt < 4; ++nt) acc[nt] = (f32x4){0.f,0.f,0.f,0.f};
    #pragma unroll
    for (int kk = 0; kk < 4; ++kk) {
      bf16x8 a = *(const bf16x8*)&qpl[w*16+i][kk*32+q*8];
      #pragma unroll
      for (int nt = 0; nt < 4; ++nt) {
        if (nt <= w) {
          bf16x8 bb = *(const bf16x8*)&kpl[nt*16+i][kk*32+q*8];
          acc[nt] = __builtin_amdgcn_mfma_f32_16x16x32_bf16(a, bb, acc[nt], 0, 0, 0);
        }
      }
    }
    short* Ac = A + c*4096;
    float rs[4] = {0.f,0.f,0.f,0.f};
    #pragma unroll
    for (int nt = 0; nt < 4; ++nt) {
      #pragma unroll
      for (int r = 0; r < 4; ++r) {
        const int t = w*16 + 4*q + r;
        const int s = nt*16 + i;
        const float v = (nt <= w && s <= t) ? acc[nt][r] : 0.f;
        rs[r] += v;
        Ac[t*64 + s] = f2bf(v);
      }
    }
    #pragma unroll
    for (int r = 0; r < 4; ++r) {
      #pragma unroll
      for (int off = 1; off < 16; off <<= 1) rs[r] += __shfl_xor(rs[r], off);
    }
    if (i == 0) {
      #pragma unroll
      for (int r = 0; r < 4; ++r) rowsum[c*64 + w*16 + 4*q + r] = rs[r];
    }
  };

  if (bid < 128) {
    scores(bid);
    __syncthreads();
    chunkkv(384 + bid);      // (c=bid, hh=1, dh=1)
  } else {
    chunkkv(bid - 128);      // units 0..383
  }
}

// ============ K3: prefix scans (129 blocks) ============
__global__ __launch_bounds__(256) void k_scan(const float* __restrict__ KVT,
    short* __restrict__ KVTb, float* __restrict__ Ksum) {
  const int tid = threadIdx.x;
  if (blockIdx.x < 128) {
    const int b = blockIdx.x >> 6;
    const int e = (blockIdx.x & 63)*256 + tid;
    const size_t base = (size_t)b*NCB*16384 + e;
    float run = 0.f;
    #pragma unroll 8
    for (int c = 0; c < NCB; ++c) {
      const float v = KVT[base + (size_t)c*16384];
      KVTb[base + (size_t)c*16384] = f2bf(run);
      run += v;
    }
    return;
  }
  const int b = tid >> 7, h = tid & 127;
  float run = 0.f;
  #pragma unroll 8
  for (int c = 0; c < NCB; ++c) {
    const int idx = (b*NCB + c)*128 + h;
    const float v = Ksum[idx];
    Ksum[idx] = run;
    run += v;
  }
}

// ============ K4: num/den + attn + Wo GEMM + residual + LN2 (256 blocks, 32 tokens each) ============
__global__ __launch_bounds__(256) void k_ao2(const short* __restrict__ Aintra,
    const short* __restrict__ Qp, const short* __restrict__ VgT,
    const short* __restrict__ KVTb, const float* __restrict__ Ksum,
    const float* __restrict__ rowsum, const float* __restrict__ Wo,
    const float* __restrict__ tokens, const float* __restrict__ g2,
    const float* __restrict__ b2, float* __restrict__ out) {
  const int bid = blockIdx.x, tid = threadIdx.x;
  const int c = bid >> 1, half = bid & 1;
  const int tb = c*CHUNK, t0 = tb + half*32;
  __shared__ __align__(16) char smem[73856];
  short (*at)[200] = (short(*)[200])smem;                // 32 x 200: A(64) | Qp(128)
  short (*bt)[200] = (short(*)[200])(smem + 12800);      // 128 x 200: Vg^T(64) | KVTb(128)
  float* ksl        = (float*)(smem + 64000);            // 128
  float (*dpart)[4] = (float(*)[4])(smem + 64512);       // 32 x 4
  float* denl       = (float*)(smem + 65024);            // 32
  short (*al)[136]  = (short(*)[136])(smem + 65152);     // 32 x 136 attn bf16
  // phase-2 (reuses the at/bt region after sync):
  short (*wl)[136]  = (short(*)[136])smem;               // 128 x 136 Wo^T bf16
  float (*tl)[132]  = (float(*)[132])(smem + 34816);     // 32 x 132 tokens fp32
  float* gl         = (float*)(smem + 51712);
  float* bl2        = (float*)(smem + 52224);
  float (*suml)[2]  = (float(*)[2])(smem + 52736);
  float (*ssql)[2]  = (float(*)[2])(smem + 52992);

  const short* Ac = Aintra + c*4096;
  for (int u = tid; u < 256; u += 256) {
    const int tr = u >> 3, c8 = (u & 7)*8;
    *(bf16x8*)&at[tr][c8] = *(const bf16x8*)&Ac[(half*32+tr)*64 + c8];
  }
  for (int u = tid; u < 512; u += 256) {
    const int tr = u >> 4, c8 = (u & 15)*8;
    *(bf16x8*)&at[tr][64 + c8] = *(const bf16x8*)&Qp[(t0+tr)*D_ + c8];
  }
  for (int u = tid; u < 1024; u += 256) {
    const int dd = u >> 3, c8 = (u & 7)*8;
    *(bf16x8*)&bt[dd][c8] = *(const bf16x8*)&VgT[dd*NTOK + tb + c8];
  }
  for (int u = tid; u < 2048; u += 256) {
    const int dd = u >> 4, c8 = (u & 15)*8;
    *(bf16x8*)&bt[dd][64 + c8] = *(const bf16x8*)&KVTb[(size_t)c*16384 + dd*D_ + c8];
  }
  if (tid < 128) ksl[tid] = Ksum[c*128 + tid];
  __syncthreads();
  if (tid < 128) {
    const int tr = tid >> 2, part = tid & 3;
    float dot = 0.f;
    #pragma unroll
    for (int h = 0; h < 32; ++h) dot += bf2f(at[tr][64 + part*32 + h]) * ksl[part*32 + h];
    dpart[tr][part] = dot;
  }
  __syncthreads();
  if (tid < 32)
    denl[tid] = fmaxf(rowsum[c*64 + half*32 + tid] + dpart[tid][0]+dpart[tid][1]+dpart[tid][2]+dpart[tid][3], EPS_ATTN);
  __syncthreads();
  const int w = tid >> 6, l = tid & 63, i = l & 15, q = l >> 4;
  const int rt = w & 1, dh = w >> 1;
  f32x4 acc[4];
  #pragma unroll
  for (int nt = 0; nt < 4; ++nt) acc[nt] = (f32x4){0.f,0.f,0.f,0.f};
  #pragma unroll
  for (int kk = 0; kk < 6; ++kk) {
    bf16x8 a = *(const bf16x8*)&at[rt*16+i][kk*32+q*8];
    #pragma unroll
    for (int nt = 0; nt < 4; ++nt) {
      bf16x8 bb = *(const bf16x8*)&bt[dh*64+nt*16+i][kk*32+q*8];
      acc[nt] = __builtin_amdgcn_mfma_f32_16x16x32_bf16(a, bb, acc[nt], 0, 0, 0);
    }
  }
  #pragma unroll
  for (int r = 0; r < 4; ++r) {
    const int t = rt*16 + 4*q + r;
    const float inv = 1.f / denl[t];
    #pragma unroll
    for (int nt = 0; nt < 4; ++nt)
      al[t][dh*64 + nt*16 + i] = f2bf(acc[nt][r] * inv);
  }
  __syncthreads();
  // ---- phase 2: Wo^T stage (fp32->bf16 transpose, FULL 16 iters), tokens stage ----
  #pragma unroll
  for (int it = 0; it < 16; ++it) {
    const int v = it*256 + tid;
    const int k = v & 127, n4 = v >> 7;   // n4 in [0,32)
    const float4 x4 = *(const float4*)&Wo[k*D_ + n4*4];
    wl[n4*4+0][k] = f2bf(x4.x);
    wl[n4*4+1][k] = f2bf(x4.y);
    wl[n4*4+2][k] = f2bf(x4.z);
    wl[n4*4+3][k] = f2bf(x4.w);
  }
  for (int u = tid; u < 1024; u += 256) {
    const int tr = u >> 5, c4 = (u & 31)*4;
    *(float4*)&tl[tr][c4] = *(const float4*)&tokens[(t0+tr)*D_ + c4];
  }
  if (tid < 128) { gl[tid] = g2[tid]; bl2[tid] = b2[tid]; }
  __syncthreads();
  f32x4 acc2[4];
  #pragma unroll
  for (int nt = 0; nt < 4; ++nt) acc2[nt] = (f32x4){0.f,0.f,0.f,0.f};
  #pragma unroll
  for (int kk = 0; kk < 4; ++kk) {
    bf16x8 a = *(const bf16x8*)&al[rt*16+i][kk*32+q*8];
    #pragma unroll
    for (int nt = 0; nt < 4; ++nt) {
      bf16x8 bb = *(const bf16x8*)&wl[dh*64+nt*16+i][kk*32+q*8];
      acc2[nt] = __builtin_amdgcn_mfma_f32_16x16x32_bf16(a, bb, acc2[nt], 0, 0, 0);
    }
  }
  float p[4][4];
  #pragma unroll
  for (int r = 0; r < 4; ++r) {
    const int t = rt*16 + 4*q + r;
    float ps = 0.f, qs = 0.f;
    #pragma unroll
    for (int nt = 0; nt < 4; ++nt) {
      const int col = dh*64 + nt*16 + i;
      const float v = tl[t][col] + 0.1f*acc2[nt][r];
      p[r][nt] = v; ps += v; qs += v*v;
    }
    #pragma unroll
    for (int off = 1; off < 16; off <<= 1) {
      ps += __shfl_xor(ps, off); qs += __shfl_xor(qs, off);
    }
    if (i == 0) { suml[t][dh] = ps; ssql[t][dh] = qs; }
  }
  __syncthreads();
  #pragma unroll
  for (int r = 0; r < 4; ++r) {
    const int t = rt*16 + 4*q + r;
    const float s = suml[t][0] + suml[t][1];
    const float qq = ssql[t][0] + ssql[t][1];
    const float mean = s*(1.f/D_);
    const float rr = rsqrtf(qq*(1.f/D_) - mean*mean + LN_EPS);
    #pragma unroll
    for (int nt = 0; nt < 4; ++nt) {
      const int col = dh*64 + nt*16 + i;
      out[(size_t)(t0+t)*D_ + col] = (p[r][nt]-mean)*rr*gl[col] + bl2[col];
    }
  }
}

extern "C" void kernel_launch(void* const* d_in, const int* in_sizes, int n_in,
                              void* d_out, int out_size, void* d_ws, size_t ws_size,
                              hipStream_t stream) {
  const float* tokens = (const float*)d_in[0];
  const float* Wq = (const float*)d_in[1];
  const float* Wk = (const float*)d_in[2];
  const float* Wv = (const float*)d_in[3];
  const float* Wg = (const float*)d_in[4];
  const float* bg = (const float*)d_in[5];
  const float* Wo = (const float*)d_in[6];
  const float* g1 = (const float*)d_in[7];
  const float* b1 = (const float*)d_in[8];
  const float* g2 = (const float*)d_in[9];
  const float* b2 = (const float*)d_in[10];

  char* base = (char*)d_ws;
  short* Qp     = (short*)(base);                        // 2MB
  short* Kp     = (short*)(base + (2u<<20));             // 2MB
  short* KpT    = (short*)(base + (4u<<20));             // 2MB
  short* VgT    = (short*)(base + (6u<<20));             // 2MB
  short* KVTb   = (short*)(base + (8u<<20));             // 4MB
  short* Aintra = (short*)(base + (12u<<20));            // 1MB
  float* rowsum = (float*)(base + (13u<<20));            // 32KB
  float* Ksum   = (float*)(base + (13u<<20) + (256u<<10)); // 64KB
  float* KVT    = (float*)(base + (16u<<20));            // 8MB

  k_qkvg<<<512, 256, 0, stream>>>(tokens, Wq, Wk, Wv, Wg, bg, g1, b1,
                                  Qp, Kp, KpT, VgT);
  k_cs<<<512, 256, 0, stream>>>(KpT, VgT, Qp, Kp, KVT, Ksum, Aintra, rowsum);
  k_scan<<<129, 256, 0, stream>>>(KVT, KVTb, Ksum);
  k_ao2<<<256, 256, 0, stream>>>(Aintra, Qp, VgT, KVTb, Ksum, rowsum, Wo,
                                 tokens, g2, b2, (float*)d_out);
}